// Round 6
// baseline (317.322 us; speedup 1.0000x reference)
//
#include <hip/hip_runtime.h>
#include <math.h>

typedef __attribute__((ext_vector_type(8))) short short8;
typedef __attribute__((ext_vector_type(4))) float f32x4;
typedef __attribute__((ext_vector_type(4))) unsigned int u32x4;
typedef __attribute__((ext_vector_type(2))) unsigned long long u64x2;

static __device__ __forceinline__ unsigned int fbits(float f) {
    union { float f; unsigned int u; } v; v.f = f; return v.u;
}
// pack two f32 -> bf16 pair in ONE v_perm_b32: {lo16: bf16(lo), hi16: bf16(hi)}
static __device__ __forceinline__ unsigned int pk(float lo, float hi) {
    return __builtin_amdgcn_perm(fbits(hi), fbits(lo), 0x07060302u);
}
static __device__ __forceinline__ float leaky(float x) { return fmaxf(x, 0.01f * x); }

static __device__ __forceinline__ f32x4 mm(short8 a, short8 b, f32x4 c) {
    return __builtin_amdgcn_mfma_f32_16x16x32_bf16(a, b, c, 0, 0, 0);
}

// LDS: row stride 18 u32. u32 cell (row, c) = bf16 pair (k=c, k=c+16) of that
// row's activation vector — simultaneously the MFMA A-layout (lane(i15,q)
// reads u64s {2q,2q+1} of row i15) and the pack target from MFMA C-layout
// (lane(i15,q) writes rows 4q+r at col i15). Same k-permutation applied to B
// fragments so the dot product is consistent (validated R3/R5).
//
// ALL LDS traffic is wave-private (every address is inside the wave's own
// 64-row window: wbase = tid & 192) and a wave's DS ops execute in order.
// Therefore NO HW barrier is needed; __threadfence_block() is used purely as
// a compiler fence at the u32-write -> u64-read type-crossing points (TBAA
// reordered these in R4 -> NaN). R5 used full __syncthreads() there: correct
// but 40% of cycles went idle on barrier stalls (VALU 51 + MFMA 9, rest idle).

__global__ __launch_bounds__(256, 6) void aero_mfma5(
    const float* __restrict__ vin, const float* __restrict__ win,
    const float* __restrict__ gW1, const float* __restrict__ gb1,
    const float* __restrict__ gW2, const float* __restrict__ gb2,
    const float* __restrict__ gWd1, const float* __restrict__ gbd1,
    const float* __restrict__ gWd2, const float* __restrict__ gbd2,
    const float* __restrict__ gbias,
    float* __restrict__ out, int nrows)
{
    __shared__ unsigned int hb32[256 * 18];
    unsigned long long* const hb64 = (unsigned long long*)hb32;
    float* const hbf = (float*)hb32;

    const int tid  = threadIdx.x;
    const int i15  = tid & 15;
    const int q    = (tid >> 4) & 3;
    const int wbase = tid & 192;          // wave-private 64-row LDS window
    int row = blockIdx.x * 256 + tid;
    if (row >= nrows) row = nrows - 1;

    // -------- weight B-fragments (per-lane VMEM; L2-resident) --------
    const int n0 = i15, n1 = i15 + 16;
    unsigned int w2a[4], w2b[4], w3a[4], w3b[4];
    {
        const float* p;
        f32x4 lo, hi;
        p = gW2 + n0 * 32 + 4 * q;  lo = *(const f32x4*)p; hi = *(const f32x4*)(p + 16);
        w2a[0] = pk(lo.x, hi.x); w2a[1] = pk(lo.y, hi.y); w2a[2] = pk(lo.z, hi.z); w2a[3] = pk(lo.w, hi.w);
        p = gW2 + n1 * 32 + 4 * q;  lo = *(const f32x4*)p; hi = *(const f32x4*)(p + 16);
        w2b[0] = pk(lo.x, hi.x); w2b[1] = pk(lo.y, hi.y); w2b[2] = pk(lo.z, hi.z); w2b[3] = pk(lo.w, hi.w);
        p = gWd1 + n0 * 32 + 4 * q; lo = *(const f32x4*)p; hi = *(const f32x4*)(p + 16);
        w3a[0] = pk(lo.x, hi.x); w3a[1] = pk(lo.y, hi.y); w3a[2] = pk(lo.z, hi.z); w3a[3] = pk(lo.w, hi.w);
        p = gWd1 + n1 * 32 + 4 * q; lo = *(const f32x4*)p; hi = *(const f32x4*)(p + 16);
        w3b[0] = pk(lo.x, hi.x); w3b[1] = pk(lo.y, hi.y); w3b[2] = pk(lo.z, hi.z); w3b[3] = pk(lo.w, hi.w);
    }
    // W1 (3->32): only quad 0, lo halves, k<3 nonzero
    unsigned int w1a[4] = {0, 0, 0, 0}, w1b[4] = {0, 0, 0, 0};
    if (q == 0) {
        const float* pa = gW1 + n0 * 3;
        const float* pb = gW1 + n1 * 3;
        w1a[0] = fbits(pa[0]) >> 16; w1a[1] = fbits(pa[1]) >> 16; w1a[2] = fbits(pa[2]) >> 16;
        w1b[0] = fbits(pb[0]) >> 16; w1b[1] = fbits(pb[1]) >> 16; w1b[2] = fbits(pb[2]) >> 16;
    }
    // Wd2 (32->3): N=3, only lanes i15<3 carry B
    unsigned int w4[4] = {0, 0, 0, 0};
    float b4 = 0.0f;
    if (i15 < 3) {
        const float* p = gWd2 + i15 * 32 + 4 * q;
        const f32x4 lo = *(const f32x4*)p;
        const f32x4 hi = *(const f32x4*)(p + 16);
        w4[0] = pk(lo.x, hi.x); w4[1] = pk(lo.y, hi.y); w4[2] = pk(lo.z, hi.z); w4[3] = pk(lo.w, hi.w);
        b4 = gbd2[i15];
    }
    const float b1a = gb1[n0],  b1b = gb1[n1];
    const float b2a = gb2[n0],  b2b = gb2[n1];
    const float b3a = gbd1[n0], b3b = gbd1[n1];

    const short8 B1a = __builtin_bit_cast(short8, (u32x4){w1a[0], w1a[1], w1a[2], w1a[3]});
    const short8 B1b = __builtin_bit_cast(short8, (u32x4){w1b[0], w1b[1], w1b[2], w1b[3]});
    const short8 B2a = __builtin_bit_cast(short8, (u32x4){w2a[0], w2a[1], w2a[2], w2a[3]});
    const short8 B2b = __builtin_bit_cast(short8, (u32x4){w2b[0], w2b[1], w2b[2], w2b[3]});
    const short8 B3a = __builtin_bit_cast(short8, (u32x4){w3a[0], w3a[1], w3a[2], w3a[3]});
    const short8 B3b = __builtin_bit_cast(short8, (u32x4){w3b[0], w3b[1], w3b[2], w3b[3]});
    const short8 B4  = __builtin_bit_cast(short8, (u32x4){w4[0],  w4[1],  w4[2],  w4[3]});

    // -------- Gram-Schmidt (lane = row) --------
    const float v0 = vin[3 * row + 0], v1 = vin[3 * row + 1], v2 = vin[3 * row + 2];
    const float w0 = win[3 * row + 0], w1 = win[3 * row + 1], w2 = win[3 * row + 2];

    const float nv  = sqrtf(v0 * v0 + v1 * v1 + v2 * v2) + 1e-8f;
    const float rnv = 1.0f / nv;
    const float a0 = v0 * rnv, a1 = v1 * rnv, a2 = v2 * rnv;       // v_on
    const float proj = w0 * a0 + w1 * a1 + w2 * a2;
    const float o0 = w0 - proj * a0, o1 = w1 - proj * a1, o2 = w2 - proj * a2;
    const float nw  = sqrtf(o0 * o0 + o1 * o1 + o2 * o2) + 1e-8f;
    const float rnw = 1.0f / nw;
    const float c0 = o0 * rnw, c1 = o1 * rnw, c2 = o2 * rnw;       // w_on
    const float u0 = a1 * c2 - a2 * c1;                            // u_on
    const float u1 = a2 * c0 - a0 * c2;
    const float u2 = a0 * c1 - a1 * c0;

    const float f0 = v0 * a0 + v1 * a1 + v2 * a2;
    const float f1 = proj;
    const float f2 = w0 * c0 + w1 * c1 + w2 * c2;

    // feat -> LDS in A-layout (k=0..2 lo halves of u32 cols 0..2; col 3 = 0)
    hb64[tid * 9 + 0] = (unsigned long long)(fbits(f0) >> 16)
                      | ((unsigned long long)(fbits(f1) >> 16) << 32);
    hb64[tid * 9 + 1] = (unsigned long long)(fbits(f2) >> 16);
    __threadfence_block();   // compiler fence: feat-write -> L1 A-read (no s_barrier)

    // -------- layer 1 MFMA: h1 = leaky(feat @ W1^T + b1), kept in C-layout ----
    float h1c[4][8];   // [m-tile][ntile0 r0..3 | ntile1 r0..3]
    #pragma unroll
    for (int t = 0; t < 4; ++t) {
        const int ra = (wbase + 16 * t + i15) * 9;
        u64x2 av;
        av.x = (q == 0) ? hb64[ra + 0] : 0ull;
        av.y = (q == 0) ? hb64[ra + 1] : 0ull;
        const short8 af = __builtin_bit_cast(short8, av);
        f32x4 acc0 = {b1a, b1a, b1a, b1a};
        f32x4 acc1 = {b1b, b1b, b1b, b1b};
        acc0 = mm(af, B1a, acc0);
        acc1 = mm(af, B1b, acc1);
        #pragma unroll
        for (int r = 0; r < 4; ++r) {
            h1c[t][r]     = leaky(acc0[r]);
            h1c[t][4 + r] = leaky(acc1[r]);
        }
    }
    // pack h1 C-layout -> LDS A-layout (WAR vs reads above is covered by the
    // per-tile data dependence; cross-tile rows are disjoint)
    #pragma unroll
    for (int t = 0; t < 4; ++t) {
        const int zr = (wbase + 16 * t + 4 * q) * 18 + i15;
        #pragma unroll
        for (int r = 0; r < 4; ++r)
            hb32[zr + 18 * r] = pk(h1c[t][r], h1c[t][4 + r]);
    }
    __threadfence_block();   // h1 pack (u32) -> L2 A-read (u64)

    // -------- layer 2 MFMA + gate: h2 = leaky(h1 @ W2^T + b2) * h1 ----------
    #pragma unroll
    for (int t = 0; t < 4; ++t) {
        const int ra = (wbase + 16 * t + i15) * 9 + 2 * q;
        u64x2 av; av.x = hb64[ra]; av.y = hb64[ra + 1];
        const short8 af = __builtin_bit_cast(short8, av);
        f32x4 acc0 = {b2a, b2a, b2a, b2a};
        f32x4 acc1 = {b2b, b2b, b2b, b2b};
        acc0 = mm(af, B2a, acc0);
        acc1 = mm(af, B2b, acc1);
        #pragma unroll
        for (int r = 0; r < 4; ++r) {
            h1c[t][r]     = leaky(acc0[r]) * h1c[t][r];   // gate in C-layout
            h1c[t][4 + r] = leaky(acc1[r]) * h1c[t][4 + r];
        }
    }
    #pragma unroll
    for (int t = 0; t < 4; ++t) {
        const int zr = (wbase + 16 * t + 4 * q) * 18 + i15;
        #pragma unroll
        for (int r = 0; r < 4; ++r)
            hb32[zr + 18 * r] = pk(h1c[t][r], h1c[t][4 + r]);
    }
    __threadfence_block();   // h2 pack -> L3 A-read

    // -------- layer 3 MFMA: h3 = leaky(h2 @ Wd1^T + bd1) ----------
    #pragma unroll
    for (int t = 0; t < 4; ++t) {
        const int ra = (wbase + 16 * t + i15) * 9 + 2 * q;
        u64x2 av; av.x = hb64[ra]; av.y = hb64[ra + 1];
        const short8 af = __builtin_bit_cast(short8, av);
        f32x4 acc0 = {b3a, b3a, b3a, b3a};
        f32x4 acc1 = {b3b, b3b, b3b, b3b};
        acc0 = mm(af, B3a, acc0);
        acc1 = mm(af, B3b, acc1);
        #pragma unroll
        for (int r = 0; r < 4; ++r) {
            h1c[t][r]     = leaky(acc0[r]);
            h1c[t][4 + r] = leaky(acc1[r]);
        }
    }
    #pragma unroll
    for (int t = 0; t < 4; ++t) {
        const int zr = (wbase + 16 * t + 4 * q) * 18 + i15;
        #pragma unroll
        for (int r = 0; r < 4; ++r)
            hb32[zr + 18 * r] = pk(h1c[t][r], h1c[t][4 + r]);
    }
    __threadfence_block();   // h3 pack -> L4 A-read

    // -------- layer 4 MFMA (32->3): y in C-layout cols 0..2, written as f32 ----
    #pragma unroll
    for (int t = 0; t < 4; ++t) {
        const int ra = (wbase + 16 * t + i15) * 9 + 2 * q;
        u64x2 av; av.x = hb64[ra]; av.y = hb64[ra + 1];
        const short8 af = __builtin_bit_cast(short8, av);
        f32x4 acc = {b4, b4, b4, b4};
        acc = mm(af, B4, acc);
        if (i15 < 3) {
            const int zr = (wbase + 16 * t + 4 * q) * 18 + i15;
            #pragma unroll
            for (int r = 0; r < 4; ++r)
                hbf[zr + 18 * r] = acc[r];
        }
    }
    __threadfence_block();   // y write (f32) -> epilogue read (f32)

    // -------- epilogue (lane = row): rotate + bias + store --------
    const float y0 = hbf[tid * 18 + 0];
    const float y1 = hbf[tid * 18 + 1];
    const float y2 = hbf[tid * 18 + 2];
    out[3 * row + 0] = fmaf(a0, y0, fmaf(c0, y1, fmaf(u0, y2, gbias[0])));
    out[3 * row + 1] = fmaf(a1, y0, fmaf(c1, y1, fmaf(u1, y2, gbias[1])));
    out[3 * row + 2] = fmaf(a2, y0, fmaf(c2, y1, fmaf(u2, y2, gbias[2])));
}

extern "C" void kernel_launch(void* const* d_in, const int* in_sizes, int n_in,
                              void* d_out, int out_size, void* d_ws, size_t ws_size,
                              hipStream_t stream) {
    const float* v    = (const float*)d_in[0];
    const float* w    = (const float*)d_in[1];
    const float* W1   = (const float*)d_in[2];
    const float* b1   = (const float*)d_in[3];
    const float* W2   = (const float*)d_in[4];
    const float* b2   = (const float*)d_in[5];
    const float* Wd1  = (const float*)d_in[6];
    const float* bd1  = (const float*)d_in[7];
    const float* Wd2  = (const float*)d_in[8];
    const float* bd2  = (const float*)d_in[9];
    const float* bias = (const float*)d_in[10];

    const int nrows = in_sizes[0] / 3;
    dim3 block(256);
    dim3 grid((nrows + 255) / 256);
    hipLaunchKernelGGL(aero_mfma5, grid, block, 0, stream,
                       v, w, W1, b1, W2, b2, Wd1, bd1, Wd2, bd2, bias,
                       (float*)d_out, nrows);
}

// Round 7
// 146.936 us; speedup vs baseline: 2.1596x; 2.1596x over previous
//
#include <hip/hip_runtime.h>
#include <math.h>

typedef __attribute__((ext_vector_type(8))) short short8;
typedef __attribute__((ext_vector_type(4))) float f32x4;
typedef __attribute__((ext_vector_type(4))) unsigned int u32x4;
typedef __attribute__((ext_vector_type(2))) unsigned long long u64x2;

static __device__ __forceinline__ unsigned int fbits(float f) {
    union { float f; unsigned int u; } v; v.f = f; return v.u;
}
// pack two f32 -> bf16 pair in ONE v_perm_b32: {lo16: bf16(lo), hi16: bf16(hi)}
static __device__ __forceinline__ unsigned int pk(float lo, float hi) {
    return __builtin_amdgcn_perm(fbits(hi), fbits(lo), 0x07060302u);
}
static __device__ __forceinline__ float leaky(float x) { return fmaxf(x, 0.01f * x); }

static __device__ __forceinline__ f32x4 mm(short8 a, short8 b, f32x4 c) {
    return __builtin_amdgcn_mfma_f32_16x16x32_bf16(a, b, c, 0, 0, 0);
}

// Pure compiler fence: pins program order of the u32 pack-writes vs the u64
// A-fragment reads (TBAA says they don't alias -> R4's NaN). Emits ZERO
// instructions -- unlike __threadfence_block(), which drains vmcnt and
// contributed to R6's stall. HW ordering is free: all LDS traffic is
// wave-private (wbase = tid & 192) and a wave's DS ops execute in order.
#define CFENCE() __asm__ volatile("" ::: "memory")

// LDS: row stride 18 u32. u32 cell (row, c) = bf16 pair (k=c, k=c+16) of that
// row's activation vector -- simultaneously the MFMA A-layout (lane(i15,q)
// reads u64s {2q,2q+1} of row i15) and the pack target from MFMA C-layout
// (lane(i15,q) writes rows 4q+r at col i15). Same k-permutation applied to B
// fragments so the dot product is consistent (validated R3/R5/R6).
//
// __launch_bounds__(256, 4): R6's (256,6) capped VGPR at ~85 -> massive spill
// (813 MB scratch HBM traffic). (256,4) gives 128 VGPR budget; R5 measured 60.

__global__ __launch_bounds__(256, 4) void aero_mfma6(
    const float* __restrict__ vin, const float* __restrict__ win,
    const float* __restrict__ gW1, const float* __restrict__ gb1,
    const float* __restrict__ gW2, const float* __restrict__ gb2,
    const float* __restrict__ gWd1, const float* __restrict__ gbd1,
    const float* __restrict__ gWd2, const float* __restrict__ gbd2,
    const float* __restrict__ gbias,
    float* __restrict__ out, int nrows)
{
    __shared__ unsigned int hb32[256 * 18];
    unsigned long long* const hb64 = (unsigned long long*)hb32;
    float* const hbf = (float*)hb32;

    const int tid  = threadIdx.x;
    const int i15  = tid & 15;
    const int q    = (tid >> 4) & 3;
    const int wbase = tid & 192;          // wave-private 64-row LDS window
    int row = blockIdx.x * 256 + tid;
    if (row >= nrows) row = nrows - 1;

    // -------- weight B-fragments (per-lane VMEM; L2-resident) --------
    const int n0 = i15, n1 = i15 + 16;
    unsigned int w2a[4], w2b[4], w3a[4], w3b[4];
    {
        const float* p;
        f32x4 lo, hi;
        p = gW2 + n0 * 32 + 4 * q;  lo = *(const f32x4*)p; hi = *(const f32x4*)(p + 16);
        w2a[0] = pk(lo.x, hi.x); w2a[1] = pk(lo.y, hi.y); w2a[2] = pk(lo.z, hi.z); w2a[3] = pk(lo.w, hi.w);
        p = gW2 + n1 * 32 + 4 * q;  lo = *(const f32x4*)p; hi = *(const f32x4*)(p + 16);
        w2b[0] = pk(lo.x, hi.x); w2b[1] = pk(lo.y, hi.y); w2b[2] = pk(lo.z, hi.z); w2b[3] = pk(lo.w, hi.w);
        p = gWd1 + n0 * 32 + 4 * q; lo = *(const f32x4*)p; hi = *(const f32x4*)(p + 16);
        w3a[0] = pk(lo.x, hi.x); w3a[1] = pk(lo.y, hi.y); w3a[2] = pk(lo.z, hi.z); w3a[3] = pk(lo.w, hi.w);
        p = gWd1 + n1 * 32 + 4 * q; lo = *(const f32x4*)p; hi = *(const f32x4*)(p + 16);
        w3b[0] = pk(lo.x, hi.x); w3b[1] = pk(lo.y, hi.y); w3b[2] = pk(lo.z, hi.z); w3b[3] = pk(lo.w, hi.w);
    }
    // W1 (3->32): only quad 0, lo halves, k<3 nonzero
    unsigned int w1a[4] = {0, 0, 0, 0}, w1b[4] = {0, 0, 0, 0};
    if (q == 0) {
        const float* pa = gW1 + n0 * 3;
        const float* pb = gW1 + n1 * 3;
        w1a[0] = fbits(pa[0]) >> 16; w1a[1] = fbits(pa[1]) >> 16; w1a[2] = fbits(pa[2]) >> 16;
        w1b[0] = fbits(pb[0]) >> 16; w1b[1] = fbits(pb[1]) >> 16; w1b[2] = fbits(pb[2]) >> 16;
    }
    // Wd2 (32->3): N=3, only lanes i15<3 carry B
    unsigned int w4[4] = {0, 0, 0, 0};
    float b4 = 0.0f;
    if (i15 < 3) {
        const float* p = gWd2 + i15 * 32 + 4 * q;
        const f32x4 lo = *(const f32x4*)p;
        const f32x4 hi = *(const f32x4*)(p + 16);
        w4[0] = pk(lo.x, hi.x); w4[1] = pk(lo.y, hi.y); w4[2] = pk(lo.z, hi.z); w4[3] = pk(lo.w, hi.w);
        b4 = gbd2[i15];
    }
    const float b1a = gb1[n0],  b1b = gb1[n1];
    const float b2a = gb2[n0],  b2b = gb2[n1];
    const float b3a = gbd1[n0], b3b = gbd1[n1];

    const short8 B1a = __builtin_bit_cast(short8, (u32x4){w1a[0], w1a[1], w1a[2], w1a[3]});
    const short8 B1b = __builtin_bit_cast(short8, (u32x4){w1b[0], w1b[1], w1b[2], w1b[3]});
    const short8 B2a = __builtin_bit_cast(short8, (u32x4){w2a[0], w2a[1], w2a[2], w2a[3]});
    const short8 B2b = __builtin_bit_cast(short8, (u32x4){w2b[0], w2b[1], w2b[2], w2b[3]});
    const short8 B3a = __builtin_bit_cast(short8, (u32x4){w3a[0], w3a[1], w3a[2], w3a[3]});
    const short8 B3b = __builtin_bit_cast(short8, (u32x4){w3b[0], w3b[1], w3b[2], w3b[3]});
    const short8 B4  = __builtin_bit_cast(short8, (u32x4){w4[0],  w4[1],  w4[2],  w4[3]});

    // -------- Gram-Schmidt (lane = row) --------
    const float v0 = vin[3 * row + 0], v1 = vin[3 * row + 1], v2 = vin[3 * row + 2];
    const float w0 = win[3 * row + 0], w1 = win[3 * row + 1], w2 = win[3 * row + 2];

    const float nv  = sqrtf(v0 * v0 + v1 * v1 + v2 * v2) + 1e-8f;
    const float rnv = 1.0f / nv;
    const float a0 = v0 * rnv, a1 = v1 * rnv, a2 = v2 * rnv;       // v_on
    const float proj = w0 * a0 + w1 * a1 + w2 * a2;
    const float o0 = w0 - proj * a0, o1 = w1 - proj * a1, o2 = w2 - proj * a2;
    const float nw  = sqrtf(o0 * o0 + o1 * o1 + o2 * o2) + 1e-8f;
    const float rnw = 1.0f / nw;
    const float c0 = o0 * rnw, c1 = o1 * rnw, c2 = o2 * rnw;       // w_on
    const float u0 = a1 * c2 - a2 * c1;                            // u_on
    const float u1 = a2 * c0 - a0 * c2;
    const float u2 = a0 * c1 - a1 * c0;

    const float f0 = v0 * a0 + v1 * a1 + v2 * a2;
    const float f1 = proj;
    const float f2 = w0 * c0 + w1 * c1 + w2 * c2;

    // feat -> LDS in A-layout (k=0..2 lo halves of u32 cols 0..2; col 3 = 0)
    hb64[tid * 9 + 0] = (unsigned long long)(fbits(f0) >> 16)
                      | ((unsigned long long)(fbits(f1) >> 16) << 32);
    hb64[tid * 9 + 1] = (unsigned long long)(fbits(f2) >> 16);
    CFENCE();   // feat-write -> L1 A-read

    // -------- layer 1 MFMA: h1 = leaky(feat @ W1^T + b1), kept in C-layout ----
    float h1c[4][8];   // [m-tile][ntile0 r0..3 | ntile1 r0..3]
    #pragma unroll
    for (int t = 0; t < 4; ++t) {
        const int ra = (wbase + 16 * t + i15) * 9;
        u64x2 av;
        av.x = (q == 0) ? hb64[ra + 0] : 0ull;
        av.y = (q == 0) ? hb64[ra + 1] : 0ull;
        const short8 af = __builtin_bit_cast(short8, av);
        f32x4 acc0 = {b1a, b1a, b1a, b1a};
        f32x4 acc1 = {b1b, b1b, b1b, b1b};
        acc0 = mm(af, B1a, acc0);
        acc1 = mm(af, B1b, acc1);
        #pragma unroll
        for (int r = 0; r < 4; ++r) {
            h1c[t][r]     = leaky(acc0[r]);
            h1c[t][4 + r] = leaky(acc1[r]);
        }
    }
    CFENCE();   // L1 A-reads before h1 pack overwrites (WAR, cross-lane)
    #pragma unroll
    for (int t = 0; t < 4; ++t) {
        const int zr = (wbase + 16 * t + 4 * q) * 18 + i15;
        #pragma unroll
        for (int r = 0; r < 4; ++r)
            hb32[zr + 18 * r] = pk(h1c[t][r], h1c[t][4 + r]);
    }
    CFENCE();   // h1 pack (u32) -> L2 A-read (u64)

    // -------- layer 2 MFMA + gate: h2 = leaky(h1 @ W2^T + b2) * h1 ----------
    #pragma unroll
    for (int t = 0; t < 4; ++t) {
        const int ra = (wbase + 16 * t + i15) * 9 + 2 * q;
        u64x2 av; av.x = hb64[ra]; av.y = hb64[ra + 1];
        const short8 af = __builtin_bit_cast(short8, av);
        f32x4 acc0 = {b2a, b2a, b2a, b2a};
        f32x4 acc1 = {b2b, b2b, b2b, b2b};
        acc0 = mm(af, B2a, acc0);
        acc1 = mm(af, B2b, acc1);
        #pragma unroll
        for (int r = 0; r < 4; ++r) {
            h1c[t][r]     = leaky(acc0[r]) * h1c[t][r];   // gate in C-layout
            h1c[t][4 + r] = leaky(acc1[r]) * h1c[t][4 + r];
        }
    }
    CFENCE();   // L2 A-reads before h2 pack (WAR)
    #pragma unroll
    for (int t = 0; t < 4; ++t) {
        const int zr = (wbase + 16 * t + 4 * q) * 18 + i15;
        #pragma unroll
        for (int r = 0; r < 4; ++r)
            hb32[zr + 18 * r] = pk(h1c[t][r], h1c[t][4 + r]);
    }
    CFENCE();   // h2 pack -> L3 A-read

    // -------- layer 3 MFMA: h3 = leaky(h2 @ Wd1^T + bd1) ----------
    #pragma unroll
    for (int t = 0; t < 4; ++t) {
        const int ra = (wbase + 16 * t + i15) * 9 + 2 * q;
        u64x2 av; av.x = hb64[ra]; av.y = hb64[ra + 1];
        const short8 af = __builtin_bit_cast(short8, av);
        f32x4 acc0 = {b3a, b3a, b3a, b3a};
        f32x4 acc1 = {b3b, b3b, b3b, b3b};
        acc0 = mm(af, B3a, acc0);
        acc1 = mm(af, B3b, acc1);
        #pragma unroll
        for (int r = 0; r < 4; ++r) {
            h1c[t][r]     = leaky(acc0[r]);
            h1c[t][4 + r] = leaky(acc1[r]);
        }
    }
    CFENCE();   // L3 A-reads before h3 pack (WAR)
    #pragma unroll
    for (int t = 0; t < 4; ++t) {
        const int zr = (wbase + 16 * t + 4 * q) * 18 + i15;
        #pragma unroll
        for (int r = 0; r < 4; ++r)
            hb32[zr + 18 * r] = pk(h1c[t][r], h1c[t][4 + r]);
    }
    CFENCE();   // h3 pack -> L4 A-read

    // -------- layer 4 MFMA (32->3): y in C-layout cols 0..2, written as f32 ----
    #pragma unroll
    for (int t = 0; t < 4; ++t) {
        const int ra = (wbase + 16 * t + i15) * 9 + 2 * q;
        u64x2 av; av.x = hb64[ra]; av.y = hb64[ra + 1];
        const short8 af = __builtin_bit_cast(short8, av);
        f32x4 acc = {b4, b4, b4, b4};
        acc = mm(af, B4, acc);
        if (i15 < 3) {
            const int zr = (wbase + 16 * t + 4 * q) * 18 + i15;
            #pragma unroll
            for (int r = 0; r < 4; ++r)
                hbf[zr + 18 * r] = acc[r];
        }
    }
    CFENCE();   // y write -> epilogue read

    // -------- epilogue (lane = row): rotate + bias + store --------
    const float y0 = hbf[tid * 18 + 0];
    const float y1 = hbf[tid * 18 + 1];
    const float y2 = hbf[tid * 18 + 2];
    out[3 * row + 0] = fmaf(a0, y0, fmaf(c0, y1, fmaf(u0, y2, gbias[0])));
    out[3 * row + 1] = fmaf(a1, y0, fmaf(c1, y1, fmaf(u1, y2, gbias[1])));
    out[3 * row + 2] = fmaf(a2, y0, fmaf(c2, y1, fmaf(u2, y2, gbias[2])));
}

extern "C" void kernel_launch(void* const* d_in, const int* in_sizes, int n_in,
                              void* d_out, int out_size, void* d_ws, size_t ws_size,
                              hipStream_t stream) {
    const float* v    = (const float*)d_in[0];
    const float* w    = (const float*)d_in[1];
    const float* W1   = (const float*)d_in[2];
    const float* b1   = (const float*)d_in[3];
    const float* W2   = (const float*)d_in[4];
    const float* b2   = (const float*)d_in[5];
    const float* Wd1  = (const float*)d_in[6];
    const float* bd1  = (const float*)d_in[7];
    const float* Wd2  = (const float*)d_in[8];
    const float* bd2  = (const float*)d_in[9];
    const float* bias = (const float*)d_in[10];

    const int nrows = in_sizes[0] / 3;
    dim3 block(256);
    dim3 grid((nrows + 255) / 256);
    hipLaunchKernelGGL(aero_mfma6, grid, block, 0, stream,
                       v, w, W1, b1, W2, b2, Wd1, bd1, Wd2, bd2, bias,
                       (float*)d_out, nrows);
}

// Round 8
// 143.652 us; speedup vs baseline: 2.2090x; 1.0229x over previous
//
#include <hip/hip_runtime.h>
#include <math.h>

typedef __attribute__((ext_vector_type(8))) short short8;
typedef __attribute__((ext_vector_type(4))) float f32x4;
typedef __attribute__((ext_vector_type(4))) unsigned int u32x4;

static __device__ __forceinline__ unsigned int fbits(float f) {
    union { float f; unsigned int u; } v; v.f = f; return v.u;
}
static __device__ __forceinline__ float bitsf(unsigned int u) {
    union { float f; unsigned int u; } v; v.u = u; return v.f;
}
// pack two f32 -> bf16 pair in ONE v_perm_b32: {lo16: bf16(lo), hi16: bf16(hi)}
static __device__ __forceinline__ unsigned int pk(float lo, float hi) {
    return __builtin_amdgcn_perm(fbits(hi), fbits(lo), 0x07060302u);
}
static __device__ __forceinline__ float leaky(float x) { return fmaxf(x, 0.01f * x); }

static __device__ __forceinline__ f32x4 mm(short8 a, short8 b, f32x4 c) {
    return __builtin_amdgcn_mfma_f32_16x16x32_bf16(a, b, c, 0, 0, 0);
}

// LDS: ONE u32 array, row stride 18. Cell (row, c) = bf16 pair (k=c, k=c+16).
// All accesses are scalar u32 -> uniform type -> compiler alias analysis:
//   - intra-tile pack-write (rows rb+4q+r, col i15) vs A-read (row rb+i15,
//     cols 4q+j) CAN collide for lanes with i15 in [4q,4q+4) -> order preserved
//     (this is the ordering R4's u32/u64 type-punning lost -> NaN);
//   - cross-tile row sets [16t,16t+16) are provably disjoint -> the 4 m-tile
//     chains (each: L1->pack->L2->gate->pack->L3->pack->L4) schedule freely,
//     giving 4-way ILP to hide LDS/MFMA latency. R7 showed barriers were NOT
//     the bottleneck (63us with vs 64us without); the serial per-wave chain +
//     global CFENCEs were. No fences, no barriers: wave-private LDS windows
//     (wbase = tid & 192) + in-order per-wave DS pipe give HW ordering free.
// Branch-free body (cndmask selects; y-write unconditional into dead columns)
// -> single basic block -> maximal scheduling freedom.

__global__ __launch_bounds__(256, 4) void aero_mfma7(
    const float* __restrict__ vin, const float* __restrict__ win,
    const float* __restrict__ gW1, const float* __restrict__ gb1,
    const float* __restrict__ gW2, const float* __restrict__ gb2,
    const float* __restrict__ gWd1, const float* __restrict__ gbd1,
    const float* __restrict__ gWd2, const float* __restrict__ gbd2,
    const float* __restrict__ gbias,
    float* __restrict__ out, int nrows)
{
    __shared__ unsigned int hb[256 * 18];

    const int tid  = threadIdx.x;
    const int i15  = tid & 15;
    const int q    = (tid >> 4) & 3;
    const int wbase = tid & 192;          // wave-private 64-row LDS window
    int row = blockIdx.x * 256 + tid;
    row = (row < nrows) ? row : (nrows - 1);

    // -------- weight B-fragments (per-lane VMEM; L2-resident) --------
    const int n0 = i15, n1 = i15 + 16;
    unsigned int w2a[4], w2b[4], w3a[4], w3b[4];
    {
        const float* p;
        f32x4 lo, hi;
        p = gW2 + n0 * 32 + 4 * q;  lo = *(const f32x4*)p; hi = *(const f32x4*)(p + 16);
        w2a[0] = pk(lo.x, hi.x); w2a[1] = pk(lo.y, hi.y); w2a[2] = pk(lo.z, hi.z); w2a[3] = pk(lo.w, hi.w);
        p = gW2 + n1 * 32 + 4 * q;  lo = *(const f32x4*)p; hi = *(const f32x4*)(p + 16);
        w2b[0] = pk(lo.x, hi.x); w2b[1] = pk(lo.y, hi.y); w2b[2] = pk(lo.z, hi.z); w2b[3] = pk(lo.w, hi.w);
        p = gWd1 + n0 * 32 + 4 * q; lo = *(const f32x4*)p; hi = *(const f32x4*)(p + 16);
        w3a[0] = pk(lo.x, hi.x); w3a[1] = pk(lo.y, hi.y); w3a[2] = pk(lo.z, hi.z); w3a[3] = pk(lo.w, hi.w);
        p = gWd1 + n1 * 32 + 4 * q; lo = *(const f32x4*)p; hi = *(const f32x4*)(p + 16);
        w3b[0] = pk(lo.x, hi.x); w3b[1] = pk(lo.y, hi.y); w3b[2] = pk(lo.z, hi.z); w3b[3] = pk(lo.w, hi.w);
    }
    // W1 (3->32): only quad 0 carries A data; B lo halves k<3 nonzero
    const int isq0 = (q == 0);
    unsigned int w1a[4] = {0, 0, 0, 0}, w1b[4] = {0, 0, 0, 0};
    {
        const float* pa = gW1 + n0 * 3;
        const float* pb = gW1 + n1 * 3;
        const unsigned int m = isq0 ? 0xFFFFFFFFu : 0u;
        w1a[0] = (fbits(pa[0]) >> 16) & m; w1a[1] = (fbits(pa[1]) >> 16) & m; w1a[2] = (fbits(pa[2]) >> 16) & m;
        w1b[0] = (fbits(pb[0]) >> 16) & m; w1b[1] = (fbits(pb[1]) >> 16) & m; w1b[2] = (fbits(pb[2]) >> 16) & m;
    }
    // Wd2 (32->3): N=3; lanes i15>=3 get zero B (their y columns are dead)
    unsigned int w4[4];
    const int wi = (i15 < 3) ? i15 : 0;
    {
        const float* p = gWd2 + wi * 32 + 4 * q;
        const f32x4 lo = *(const f32x4*)p;
        const f32x4 hi = *(const f32x4*)(p + 16);
        const unsigned int m = (i15 < 3) ? 0xFFFFFFFFu : 0u;
        w4[0] = pk(lo.x, hi.x) & m; w4[1] = pk(lo.y, hi.y) & m;
        w4[2] = pk(lo.z, hi.z) & m; w4[3] = pk(lo.w, hi.w) & m;
    }
    const float b4  = (i15 < 3) ? gbd2[wi] : 0.0f;
    const float b1a = gb1[n0],  b1b = gb1[n1];
    const float b2a = gb2[n0],  b2b = gb2[n1];
    const float b3a = gbd1[n0], b3b = gbd1[n1];

    const short8 B1a = __builtin_bit_cast(short8, (u32x4){w1a[0], w1a[1], w1a[2], w1a[3]});
    const short8 B1b = __builtin_bit_cast(short8, (u32x4){w1b[0], w1b[1], w1b[2], w1b[3]});
    const short8 B2a = __builtin_bit_cast(short8, (u32x4){w2a[0], w2a[1], w2a[2], w2a[3]});
    const short8 B2b = __builtin_bit_cast(short8, (u32x4){w2b[0], w2b[1], w2b[2], w2b[3]});
    const short8 B3a = __builtin_bit_cast(short8, (u32x4){w3a[0], w3a[1], w3a[2], w3a[3]});
    const short8 B3b = __builtin_bit_cast(short8, (u32x4){w3b[0], w3b[1], w3b[2], w3b[3]});
    const short8 B4  = __builtin_bit_cast(short8, (u32x4){w4[0],  w4[1],  w4[2],  w4[3]});

    // -------- Gram-Schmidt (lane = row) --------
    const float v0 = vin[3 * row + 0], v1 = vin[3 * row + 1], v2 = vin[3 * row + 2];
    const float w0 = win[3 * row + 0], w1 = win[3 * row + 1], w2 = win[3 * row + 2];

    const float nv  = sqrtf(v0 * v0 + v1 * v1 + v2 * v2) + 1e-8f;
    const float rnv = 1.0f / nv;
    const float a0 = v0 * rnv, a1 = v1 * rnv, a2 = v2 * rnv;       // v_on
    const float proj = w0 * a0 + w1 * a1 + w2 * a2;
    const float o0 = w0 - proj * a0, o1 = w1 - proj * a1, o2 = w2 - proj * a2;
    const float nw  = sqrtf(o0 * o0 + o1 * o1 + o2 * o2) + 1e-8f;
    const float rnw = 1.0f / nw;
    const float c0 = o0 * rnw, c1 = o1 * rnw, c2 = o2 * rnw;       // w_on
    const float u0 = a1 * c2 - a2 * c1;                            // u_on
    const float u1 = a2 * c0 - a0 * c2;
    const float u2 = a0 * c1 - a1 * c0;

    const float f0 = v0 * a0 + v1 * a1 + v2 * a2;
    const float f1 = proj;
    const float f2 = w0 * c0 + w1 * c1 + w2 * c2;

    // feat -> LDS cells 0..3 of own row (cell 3 = 0 so L1 A-frag k=3,19 are 0)
    hb[tid * 18 + 0] = fbits(f0) >> 16;
    hb[tid * 18 + 1] = fbits(f1) >> 16;
    hb[tid * 18 + 2] = fbits(f2) >> 16;
    hb[tid * 18 + 3] = 0u;

    // -------- 4 independent per-tile fused chains --------
    #pragma unroll
    for (int t = 0; t < 4; ++t) {
        const int rb = wbase + 16 * t;
        const int rdbase = (rb + i15) * 18;        // A-read row
        const int wrbase = (rb + 4 * q) * 18 + i15; // pack-write base

        // ---- L1: h1 = leaky(feat @ W1^T + b1) ----
        unsigned int c0_ = hb[rdbase + 0], c1_ = hb[rdbase + 1];
        unsigned int c2_ = hb[rdbase + 2], c3_ = hb[rdbase + 3];
        c0_ = isq0 ? c0_ : 0u; c1_ = isq0 ? c1_ : 0u;
        c2_ = isq0 ? c2_ : 0u; c3_ = isq0 ? c3_ : 0u;
        short8 af = __builtin_bit_cast(short8, (u32x4){c0_, c1_, c2_, c3_});
        f32x4 acc0 = {b1a, b1a, b1a, b1a};
        f32x4 acc1 = {b1b, b1b, b1b, b1b};
        acc0 = mm(af, B1a, acc0);
        acc1 = mm(af, B1b, acc1);
        float h1[8];
        #pragma unroll
        for (int r = 0; r < 4; ++r) {
            h1[r]     = leaky(acc0[r]);
            h1[4 + r] = leaky(acc1[r]);
        }
        #pragma unroll
        for (int r = 0; r < 4; ++r)
            hb[wrbase + 18 * r] = pk(h1[r], h1[4 + r]);

        // ---- L2 + gate: h2 = leaky(h1 @ W2^T + b2) * h1 ----
        af = __builtin_bit_cast(short8, (u32x4){hb[rdbase + 4 * q + 0], hb[rdbase + 4 * q + 1],
                                                hb[rdbase + 4 * q + 2], hb[rdbase + 4 * q + 3]});
        acc0 = (f32x4){b2a, b2a, b2a, b2a};
        acc1 = (f32x4){b2b, b2b, b2b, b2b};
        acc0 = mm(af, B2a, acc0);
        acc1 = mm(af, B2b, acc1);
        #pragma unroll
        for (int r = 0; r < 4; ++r) {
            h1[r]     = leaky(acc0[r]) * h1[r];     // same C-layout cell
            h1[4 + r] = leaky(acc1[r]) * h1[4 + r];
        }
        #pragma unroll
        for (int r = 0; r < 4; ++r)
            hb[wrbase + 18 * r] = pk(h1[r], h1[4 + r]);

        // ---- L3: h3 = leaky(h2 @ Wd1^T + bd1) ----
        af = __builtin_bit_cast(short8, (u32x4){hb[rdbase + 4 * q + 0], hb[rdbase + 4 * q + 1],
                                                hb[rdbase + 4 * q + 2], hb[rdbase + 4 * q + 3]});
        acc0 = (f32x4){b3a, b3a, b3a, b3a};
        acc1 = (f32x4){b3b, b3b, b3b, b3b};
        acc0 = mm(af, B3a, acc0);
        acc1 = mm(af, B3b, acc1);
        #pragma unroll
        for (int r = 0; r < 4; ++r) {
            h1[r]     = leaky(acc0[r]);
            h1[4 + r] = leaky(acc1[r]);
        }
        #pragma unroll
        for (int r = 0; r < 4; ++r)
            hb[wrbase + 18 * r] = pk(h1[r], h1[4 + r]);

        // ---- L4 (32->3): y in C-layout; all lanes write (cols>=3 are dead) ----
        af = __builtin_bit_cast(short8, (u32x4){hb[rdbase + 4 * q + 0], hb[rdbase + 4 * q + 1],
                                                hb[rdbase + 4 * q + 2], hb[rdbase + 4 * q + 3]});
        f32x4 acc = {b4, b4, b4, b4};
        acc = mm(af, B4, acc);
        #pragma unroll
        for (int r = 0; r < 4; ++r)
            hb[wrbase + 18 * r] = fbits(acc[r]);   // f32 bits as u32
    }

    // -------- epilogue (lane = row): rotate + bias + store --------
    const float y0 = bitsf(hb[tid * 18 + 0]);
    const float y1 = bitsf(hb[tid * 18 + 1]);
    const float y2 = bitsf(hb[tid * 18 + 2]);
    out[3 * row + 0] = fmaf(a0, y0, fmaf(c0, y1, fmaf(u0, y2, gbias[0])));
    out[3 * row + 1] = fmaf(a1, y0, fmaf(c1, y1, fmaf(u1, y2, gbias[1])));
    out[3 * row + 2] = fmaf(a2, y0, fmaf(c2, y1, fmaf(u2, y2, gbias[2])));
}

extern "C" void kernel_launch(void* const* d_in, const int* in_sizes, int n_in,
                              void* d_out, int out_size, void* d_ws, size_t ws_size,
                              hipStream_t stream) {
    const float* v    = (const float*)d_in[0];
    const float* w    = (const float*)d_in[1];
    const float* W1   = (const float*)d_in[2];
    const float* b1   = (const float*)d_in[3];
    const float* W2   = (const float*)d_in[4];
    const float* b2   = (const float*)d_in[5];
    const float* Wd1  = (const float*)d_in[6];
    const float* bd1  = (const float*)d_in[7];
    const float* Wd2  = (const float*)d_in[8];
    const float* bd2  = (const float*)d_in[9];
    const float* bias = (const float*)d_in[10];

    const int nrows = in_sizes[0] / 3;
    dim3 block(256);
    dim3 grid((nrows + 255) / 256);
    hipLaunchKernelGGL(aero_mfma7, grid, block, 0, stream,
                       v, w, W1, b1, W2, b2, Wd1, bd1, Wd2, bd2, bias,
                       (float*)d_out, nrows);
}